// Round 1
// baseline (369.994 us; speedup 1.0000x reference)
//
#include <hip/hip_runtime.h>

#define B_ 256
#define T_ 256
#define C_ 384
#define H_ 384

typedef float f4 __attribute__((ext_vector_type(4)));
typedef float f32x4 __attribute__((ext_vector_type(4)));
typedef short bf8 __attribute__((ext_vector_type(8)));
typedef short s8v __attribute__((ext_vector_type(8)));
typedef short s4v __attribute__((ext_vector_type(4)));

__device__ __forceinline__ short f2bf(float f) {
  unsigned u = __builtin_bit_cast(unsigned, f);
  u += 0x7FFFu + ((u >> 16) & 1u);   // RNE; inputs are finite
  return (short)(u >> 16);
}

__device__ __forceinline__ void gload_lds16(const void* g, void* l) {
  __builtin_amdgcn_global_load_lds(
      (const __attribute__((address_space(1))) unsigned int*)g,
      (__attribute__((address_space(3))) unsigned int*)l, 16, 0, 0);
}

// ---------------------------------------------------------------------------
// Kernel 1: fp32 -> bf16 conversion for x and the three weight matrices.
// xb: [B*T][C] bf16; wb: [3*H][C] bf16 with row blocks = Wk, Wq, Wv.
// ---------------------------------------------------------------------------
__global__ __launch_bounds__(256) void convert_kernel(
    const float* __restrict__ x, const float* __restrict__ wk,
    const float* __restrict__ wq, const float* __restrict__ wv,
    short* __restrict__ xb, short* __restrict__ wb) {
  const int NXG = (B_ * T_ * C_) / 8;  // 3145728 groups of 8
  const int NWG = (H_ * C_) / 8;       // 18432 per W
  const int total = NXG + 3 * NWG;
  for (int g = blockIdx.x * 256 + threadIdx.x; g < total; g += gridDim.x * 256) {
    const float* src;
    short* dst;
    if (g < NXG) {
      src = x + (size_t)g * 8;
      dst = xb + (size_t)g * 8;
    } else {
      int h = g - NXG;
      int wsel = h / NWG;
      int o = h - wsel * NWG;
      const float* wp = wsel == 0 ? wk : (wsel == 1 ? wq : wv);
      src = wp + (size_t)o * 8;
      dst = wb + (size_t)wsel * (H_ * C_) + (size_t)o * 8;
    }
    f4 f0 = *(const f4*)src;
    f4 f1 = *(const f4*)(src + 4);
    s8v r;
    r[0] = f2bf(f0[0]); r[1] = f2bf(f0[1]); r[2] = f2bf(f0[2]); r[3] = f2bf(f0[3]);
    r[4] = f2bf(f1[0]); r[5] = f2bf(f1[1]); r[6] = f2bf(f1[2]); r[7] = f2bf(f1[3]);
    *(s8v*)dst = r;
  }
}

// ---------------------------------------------------------------------------
// Kernel 2: QKV projection GEMM.  C[m][n] = sum_k xb[m][k] * wb[n][k]
// M=65536, N=1152, K=384.  128x128 tile, BK=64, 4 waves (2x2, 64x64 each),
// 16x16x32 bf16 MFMA, global_load_lds(16B) staging.
// Output: proj 0 -> kb [B,T,H], proj 1 -> qbuf [B,T,H], proj 2 -> vt [B,H,T].
// ---------------------------------------------------------------------------
__global__ __launch_bounds__(256) void proj_gemm(
    const short* __restrict__ xb, const short* __restrict__ wb,
    short* __restrict__ kb, short* __restrict__ qbuf, short* __restrict__ vt) {
  __shared__ __align__(16) short lA[128 * 64];
  __shared__ __align__(16) short lB[128 * 64];
  const int tid = threadIdx.x;
  const int nb = blockIdx.x % 9;
  const int mb = blockIdx.x / 9;     // n-fastest: 9 blocks share an A panel
  const int m0 = mb * 128, gn0 = nb * 128;
  const int w = tid >> 6, l = tid & 63;
  const int wr = w >> 1, wc = w & 1;
  f32x4 acc[4][4] = {};
  for (int kc = 0; kc < 6; ++kc) {
    const int k0 = kc * 64;
#pragma unroll
    for (int j = 0; j < 4; ++j) {
      const int flat = j * 256 + tid;
      const int row = flat >> 3, colg = (flat & 7) * 8;
      gload_lds16(xb + (size_t)(m0 + row) * C_ + k0 + colg, (char*)lA + flat * 16);
      gload_lds16(wb + (size_t)(gn0 + row) * C_ + k0 + colg, (char*)lB + flat * 16);
    }
    __syncthreads();
#pragma unroll
    for (int ks = 0; ks < 2; ++ks) {
      const int kk = ks * 32 + (l >> 4) * 8;
      bf8 av[4], bv[4];
#pragma unroll
      for (int mt = 0; mt < 4; ++mt)
        av[mt] = *(const bf8*)&lA[(wr * 64 + mt * 16 + (l & 15)) * 64 + kk];
#pragma unroll
      for (int nt = 0; nt < 4; ++nt)
        bv[nt] = *(const bf8*)&lB[(wc * 64 + nt * 16 + (l & 15)) * 64 + kk];
#pragma unroll
      for (int mt = 0; mt < 4; ++mt)
#pragma unroll
        for (int nt = 0; nt < 4; ++nt)
          acc[mt][nt] = __builtin_amdgcn_mfma_f32_16x16x32_bf16(
              av[mt], bv[nt], acc[mt][nt], 0, 0, 0);
    }
    __syncthreads();
  }
  // epilogue: C/D layout col = lane&15, row = (lane>>4)*4 + r
  const int proj = nb / 3;
  const int gcb = (nb % 3) * 128 + wc * 64 + (l & 15);
  const int tok0 = m0 + wr * 64 + ((l >> 4) * 4);
  if (proj < 2) {
    short* dst = proj == 0 ? kb : qbuf;
#pragma unroll
    for (int mt = 0; mt < 4; ++mt)
#pragma unroll
      for (int nt = 0; nt < 4; ++nt)
#pragma unroll
        for (int r = 0; r < 4; ++r)
          dst[(size_t)(tok0 + mt * 16 + r) * H_ + gcb + nt * 16] =
              f2bf(acc[mt][nt][r]);
  } else {
    // V stored transposed: vt[b][h][t]; 4 consecutive t -> one 8B store
    const int bb = tok0 >> 8;
    const int tl0 = tok0 & 255;
#pragma unroll
    for (int mt = 0; mt < 4; ++mt)
#pragma unroll
      for (int nt = 0; nt < 4; ++nt) {
        s4v pk;
        pk[0] = f2bf(acc[mt][nt][0]); pk[1] = f2bf(acc[mt][nt][1]);
        pk[2] = f2bf(acc[mt][nt][2]); pk[3] = f2bf(acc[mt][nt][3]);
        *(s4v*)&vt[(size_t)bb * (H_ * T_) + (size_t)(gcb + nt * 16) * T_ +
                   tl0 + mt * 16] = pk;
      }
  }
}

// ---------------------------------------------------------------------------
// Kernel 3: causal attention. One block = (batch, 64-row Q block), 4 waves.
// Phase 1: S = Q K^T (K staged in LDS per 64-wide h-chunk, causal-truncated).
// Phase 2: scale+mask+softmax in registers (shfl_xor over 16 col-lanes).
// Phase 3: P (bf16) -> LDS (reuses K region).
// Phase 4: O = P @ V, V^T fragments straight from global (L2-hot).
// LDS: K 32KB @0 | Q 8KB @32768 ; P 32KB @0 (reuse).  40KB -> 4 blocks/CU.
// ---------------------------------------------------------------------------
__global__ __launch_bounds__(256) void attn_kernel(
    const short* __restrict__ qbuf, const short* __restrict__ kb,
    const short* __restrict__ vt, float* __restrict__ out) {
  __shared__ __align__(16) char smem[40960];
  short* Kl = (short*)smem;
  short* Ql = (short*)(smem + 32768);
  short* Pl = (short*)smem;
  const int b = blockIdx.x >> 2;
  const int qi = blockIdx.x & 3;
  const int t0 = qi * 64;
  const int SKV = t0 + 64;      // keys needed (causal)
  const int ntile = SKV >> 4;   // 4,8,12,16
  const int tid = threadIdx.x;
  const int w = tid >> 6, l = tid & 63;
  f32x4 sa[16] = {};
  for (int hc = 0; hc < 6; ++hc) {
    const int h0 = hc * 64;
#pragma unroll
    for (int j = 0; j < 2; ++j) {  // Q chunk: 64x64 bf16 = 8KB
      const int flat = j * 256 + tid;
      const int row = flat >> 3, colg = (flat & 7) * 8;
      gload_lds16(qbuf + (size_t)(b * T_ + t0 + row) * H_ + h0 + colg,
                  (char*)Ql + flat * 16);
    }
    const int kiss = SKV >> 5;   // K chunk: SKV x 64 bf16
    for (int j = 0; j < kiss; ++j) {
      const int flat = j * 256 + tid;
      const int row = flat >> 3, colg = (flat & 7) * 8;
      gload_lds16(kb + (size_t)(b * T_ + row) * H_ + h0 + colg,
                  (char*)Kl + flat * 16);
    }
    __syncthreads();
#pragma unroll
    for (int ks = 0; ks < 2; ++ks) {
      const int kk = ks * 32 + (l >> 4) * 8;
      bf8 av = *(const bf8*)&Ql[(w * 16 + (l & 15)) * 64 + kk];
#pragma unroll
      for (int nt = 0; nt < 16; ++nt)
        if (nt < ntile) {
          bf8 bv = *(const bf8*)&Kl[(nt * 16 + (l & 15)) * 64 + kk];
          sa[nt] = __builtin_amdgcn_mfma_f32_16x16x32_bf16(av, bv, sa[nt], 0, 0, 0);
        }
    }
    __syncthreads();
  }
  // softmax: lane holds rows rbl..rbl+3, cols nt*16 + (l&15)
  const float scale = 0.05103103630798287f;  // 384^-0.5
  const int rbl = w * 16 + (l >> 4) * 4;
#pragma unroll
  for (int r = 0; r < 4; ++r) {
    const int trow = t0 + rbl + r;
    float vv[16];
    float m = -3.0e38f;
#pragma unroll
    for (int nt = 0; nt < 16; ++nt)
      if (nt < ntile) {
        const int col = nt * 16 + (l & 15);
        float v = sa[nt][r] * scale;
        if (col > trow) v = -3.0e38f;  // causal mask
        vv[nt] = v;
        m = fmaxf(m, v);
      }
    m = fmaxf(m, __shfl_xor(m, 1));
    m = fmaxf(m, __shfl_xor(m, 2));
    m = fmaxf(m, __shfl_xor(m, 4));
    m = fmaxf(m, __shfl_xor(m, 8));
    float s = 0.f;
#pragma unroll
    for (int nt = 0; nt < 16; ++nt)
      if (nt < ntile) {
        vv[nt] = __expf(vv[nt] - m);
        s += vv[nt];
      }
    s += __shfl_xor(s, 1);
    s += __shfl_xor(s, 2);
    s += __shfl_xor(s, 4);
    s += __shfl_xor(s, 8);
    const float inv = 1.0f / s;
#pragma unroll
    for (int nt = 0; nt < 16; ++nt)
      if (nt < ntile)
        Pl[(rbl + r) * 256 + nt * 16 + (l & 15)] = f2bf(vv[nt] * inv);
  }
  __syncthreads();
  // PV: waves split D (96 cols each), all 64 rows; K-loop over keys
  f32x4 o[4][6] = {};
  const int nks = SKV >> 5;
  for (int ks = 0; ks < nks; ++ks) {
    const int kk = ks * 32 + (l >> 4) * 8;
    bf8 av[4];
#pragma unroll
    for (int mt = 0; mt < 4; ++mt)
      av[mt] = *(const bf8*)&Pl[(mt * 16 + (l & 15)) * 256 + kk];
#pragma unroll
    for (int nt = 0; nt < 6; ++nt) {
      const int d = w * 96 + nt * 16 + (l & 15);
      bf8 bv = *(const bf8*)&vt[(size_t)b * (H_ * T_) + (size_t)d * T_ + kk];
#pragma unroll
      for (int mt = 0; mt < 4; ++mt)
        o[mt][nt] = __builtin_amdgcn_mfma_f32_16x16x32_bf16(av[mt], bv, o[mt][nt], 0, 0, 0);
    }
  }
#pragma unroll
  for (int mt = 0; mt < 4; ++mt) {
    const int tok = b * T_ + t0 + mt * 16 + (l >> 4) * 4;
#pragma unroll
    for (int nt = 0; nt < 6; ++nt) {
      const int d = w * 96 + nt * 16 + (l & 15);
#pragma unroll
      for (int r = 0; r < 4; ++r)
        out[(size_t)(tok + r) * H_ + d] = o[mt][nt][r];
    }
  }
}

// ---------------------------------------------------------------------------
extern "C" void kernel_launch(void* const* d_in, const int* in_sizes, int n_in,
                              void* d_out, int out_size, void* d_ws, size_t ws_size,
                              hipStream_t stream) {
  (void)in_sizes; (void)n_in; (void)out_size; (void)ws_size;
  const float* x = (const float*)d_in[0];
  const float* wk = (const float*)d_in[1];
  const float* wq = (const float*)d_in[2];
  const float* wv = (const float*)d_in[3];
  float* out = (float*)d_out;
  char* ws = (char*)d_ws;
  const size_t SZ = (size_t)B_ * T_ * H_ * 2;  // 50,331,648 B per bf16 tensor
  short* kbuf = (short*)ws;             // K  [B,T,H] bf16
  short* qbuf = (short*)(ws + SZ);      // Q  [B,T,H] bf16
  short* vt   = (short*)(ws + 2 * SZ);  // V^T [B,H,T] bf16
  // xb/wb scratch lives in d_out (f32 output, 100.6 MB); it is only read by
  // proj_gemm, which completes before attn_kernel overwrites d_out.
  short* xb = (short*)d_out;                    // [B*T][C] bf16 (50.3 MB)
  short* wb = (short*)((char*)d_out + SZ);      // [3*H][C] bf16 (0.88 MB)
  convert_kernel<<<2048, 256, 0, stream>>>(x, wk, wq, wv, xb, wb);
  proj_gemm<<<4608, 256, 0, stream>>>(xb, wb, kbuf, qbuf, vt);
  attn_kernel<<<1024, 256, 0, stream>>>(qbuf, kbuf, vt, out);
}

// Round 2
// 339.572 us; speedup vs baseline: 1.0896x; 1.0896x over previous
//
#include <hip/hip_runtime.h>

#define B_ 256
#define T_ 256
#define C_ 384
#define H_ 384

typedef float f4 __attribute__((ext_vector_type(4)));
typedef float f32x4 __attribute__((ext_vector_type(4)));
typedef short bf8 __attribute__((ext_vector_type(8)));
typedef short s8v __attribute__((ext_vector_type(8)));
typedef short s4v __attribute__((ext_vector_type(4)));

__device__ __forceinline__ short f2bf(float f) {
  unsigned u = __builtin_bit_cast(unsigned, f);
  u += 0x7FFFu + ((u >> 16) & 1u);   // RNE; inputs are finite
  return (short)(u >> 16);
}

__device__ __forceinline__ void gload_lds16(const void* g, void* l) {
  __builtin_amdgcn_global_load_lds(
      (const __attribute__((address_space(1))) unsigned int*)g,
      (__attribute__((address_space(3))) unsigned int*)l, 16, 0, 0);
}

// ---------------------------------------------------------------------------
// Kernel 1: fp32 -> bf16 conversion for x and the three weight matrices.
// ---------------------------------------------------------------------------
__global__ __launch_bounds__(256) void convert_kernel(
    const float* __restrict__ x, const float* __restrict__ wk,
    const float* __restrict__ wq, const float* __restrict__ wv,
    short* __restrict__ xb, short* __restrict__ wb) {
  const int NXG = (B_ * T_ * C_) / 8;
  const int NWG = (H_ * C_) / 8;
  const int total = NXG + 3 * NWG;
  for (int g = blockIdx.x * 256 + threadIdx.x; g < total; g += gridDim.x * 256) {
    const float* src;
    short* dst;
    if (g < NXG) {
      src = x + (size_t)g * 8;
      dst = xb + (size_t)g * 8;
    } else {
      int h = g - NXG;
      int wsel = h / NWG;
      int o = h - wsel * NWG;
      const float* wp = wsel == 0 ? wk : (wsel == 1 ? wq : wv);
      src = wp + (size_t)o * 8;
      dst = wb + (size_t)wsel * (H_ * C_) + (size_t)o * 8;
    }
    f4 f0 = *(const f4*)src;
    f4 f1 = *(const f4*)(src + 4);
    s8v r;
    r[0] = f2bf(f0[0]); r[1] = f2bf(f0[1]); r[2] = f2bf(f0[2]); r[3] = f2bf(f0[3]);
    r[4] = f2bf(f1[0]); r[5] = f2bf(f1[1]); r[6] = f2bf(f1[2]); r[7] = f2bf(f1[3]);
    *(s8v*)dst = r;
  }
}

// ---------------------------------------------------------------------------
// Kernel 2: QKV projection GEMM, 128x128 tile, BK=64, 4 waves.
// T2: LDS tiles XOR-swizzled (source-preswizzled for global_load_lds; rule 21).
// T1: XCD-aware block swizzle (nwg=4608 divisible by 8 -> bijective).
// ---------------------------------------------------------------------------
__global__ __launch_bounds__(256) void proj_gemm(
    const short* __restrict__ xb, const short* __restrict__ wb,
    short* __restrict__ kb, short* __restrict__ qbuf, short* __restrict__ vt) {
  __shared__ __align__(16) short lA[128 * 64];
  __shared__ __align__(16) short lB[128 * 64];
  const int tid = threadIdx.x;
  // XCD swizzle: consecutive post-swizzle ids stay on one XCD -> A-panel L2 reuse
  const int cpx = 4608 / 8;
  const int bid = blockIdx.x;
  const int swz = (bid & 7) * cpx + (bid >> 3);
  const int nb = swz % 9;
  const int mb = swz / 9;
  const int m0 = mb * 128, gn0 = nb * 128;
  const int w = tid >> 6, l = tid & 63;
  const int wr = w >> 1, wc = w & 1;
  f32x4 acc[4][4] = {};
  for (int kc = 0; kc < 6; ++kc) {
    const int k0 = kc * 64;
#pragma unroll
    for (int j = 0; j < 4; ++j) {
      const int flat = j * 256 + tid;
      const int row = flat >> 3;
      // source pre-swizzle: granule g' = g ^ (row&7); LDS dest stays linear
      const int colg = ((flat & 7) ^ (row & 7)) * 8;
      gload_lds16(xb + (size_t)(m0 + row) * C_ + k0 + colg, (char*)lA + flat * 16);
      gload_lds16(wb + (size_t)(gn0 + row) * C_ + k0 + colg, (char*)lB + flat * 16);
    }
    __syncthreads();
#pragma unroll
    for (int ks = 0; ks < 2; ++ks) {
      const int kg = ks * 4 + (l >> 4);   // K-granule index 0..7
      bf8 av[4], bv[4];
#pragma unroll
      for (int mt = 0; mt < 4; ++mt) {
        const int ra = wr * 64 + mt * 16 + (l & 15);
        av[mt] = *(const bf8*)&lA[ra * 64 + ((kg ^ (ra & 7)) << 3)];
      }
#pragma unroll
      for (int nt = 0; nt < 4; ++nt) {
        const int rb = wc * 64 + nt * 16 + (l & 15);
        bv[nt] = *(const bf8*)&lB[rb * 64 + ((kg ^ (rb & 7)) << 3)];
      }
#pragma unroll
      for (int mt = 0; mt < 4; ++mt)
#pragma unroll
        for (int nt = 0; nt < 4; ++nt)
          acc[mt][nt] = __builtin_amdgcn_mfma_f32_16x16x32_bf16(
              av[mt], bv[nt], acc[mt][nt], 0, 0, 0);
    }
    __syncthreads();
  }
  const int proj = nb / 3;
  const int gcb = (nb % 3) * 128 + wc * 64 + (l & 15);
  const int tok0 = m0 + wr * 64 + ((l >> 4) * 4);
  if (proj < 2) {
    short* dst = proj == 0 ? kb : qbuf;
#pragma unroll
    for (int mt = 0; mt < 4; ++mt)
#pragma unroll
      for (int nt = 0; nt < 4; ++nt)
#pragma unroll
        for (int r = 0; r < 4; ++r)
          dst[(size_t)(tok0 + mt * 16 + r) * H_ + gcb + nt * 16] =
              f2bf(acc[mt][nt][r]);
  } else {
    const int bb = tok0 >> 8;
    const int tl0 = tok0 & 255;
#pragma unroll
    for (int mt = 0; mt < 4; ++mt)
#pragma unroll
      for (int nt = 0; nt < 4; ++nt) {
        s4v pk;
        pk[0] = f2bf(acc[mt][nt][0]); pk[1] = f2bf(acc[mt][nt][1]);
        pk[2] = f2bf(acc[mt][nt][2]); pk[3] = f2bf(acc[mt][nt][3]);
        *(s4v*)&vt[(size_t)bb * (H_ * T_) + (size_t)(gcb + nt * 16) * T_ +
                   tl0 + mt * 16] = pk;
      }
  }
}

// ---------------------------------------------------------------------------
// Kernel 3: causal attention, block = (batch, 64 q-rows), 4 waves.
// All LDS tiles XOR-swizzled: Q/K via pre-swizzled global source (rule 21),
// P via swizzled write + swizzled read.
// ---------------------------------------------------------------------------
__global__ __launch_bounds__(256) void attn_kernel(
    const short* __restrict__ qbuf, const short* __restrict__ kb,
    const short* __restrict__ vt, float* __restrict__ out) {
  __shared__ __align__(16) char smem[40960];
  short* Kl = (short*)smem;
  short* Ql = (short*)(smem + 32768);
  short* Pl = (short*)smem;
  const int b = blockIdx.x >> 2;
  const int qi = blockIdx.x & 3;
  const int t0 = qi * 64;
  const int SKV = t0 + 64;
  const int ntile = SKV >> 4;
  const int tid = threadIdx.x;
  const int w = tid >> 6, l = tid & 63;
  f32x4 sa[16] = {};
  for (int hc = 0; hc < 6; ++hc) {
    const int h0 = hc * 64;
#pragma unroll
    for (int j = 0; j < 2; ++j) {
      const int flat = j * 256 + tid;
      const int row = flat >> 3;
      const int colg = ((flat & 7) ^ (row & 7)) * 8;
      gload_lds16(qbuf + (size_t)(b * T_ + t0 + row) * H_ + h0 + colg,
                  (char*)Ql + flat * 16);
    }
    const int kiss = SKV >> 5;
    for (int j = 0; j < kiss; ++j) {
      const int flat = j * 256 + tid;
      const int row = flat >> 3;
      const int colg = ((flat & 7) ^ (row & 7)) * 8;
      gload_lds16(kb + (size_t)(b * T_ + row) * H_ + h0 + colg,
                  (char*)Kl + flat * 16);
    }
    __syncthreads();
#pragma unroll
    for (int ks = 0; ks < 2; ++ks) {
      const int kg = ks * 4 + (l >> 4);   // K-granule 0..7
      const int rq = w * 16 + (l & 15);
      bf8 av = *(const bf8*)&Ql[rq * 64 + ((kg ^ (rq & 7)) << 3)];
#pragma unroll
      for (int nt = 0; nt < 16; ++nt)
        if (nt < ntile) {
          const int rk = nt * 16 + (l & 15);
          bf8 bv = *(const bf8*)&Kl[rk * 64 + ((kg ^ (rk & 7)) << 3)];
          sa[nt] = __builtin_amdgcn_mfma_f32_16x16x32_bf16(av, bv, sa[nt], 0, 0, 0);
        }
    }
    __syncthreads();
  }
  // softmax: lane holds rows rbl..rbl+3, cols nt*16 + (l&15)
  const float scale = 0.05103103630798287f;  // 384^-0.5
  const int rbl = w * 16 + (l >> 4) * 4;
#pragma unroll
  for (int r = 0; r < 4; ++r) {
    const int prow = rbl + r;           // row within tile
    const int trow = t0 + prow;
    float vv[16];
    float m = -3.0e38f;
#pragma unroll
    for (int nt = 0; nt < 16; ++nt)
      if (nt < ntile) {
        const int col = nt * 16 + (l & 15);
        float v = sa[nt][r] * scale;
        if (col > trow) v = -3.0e38f;
        vv[nt] = v;
        m = fmaxf(m, v);
      }
    m = fmaxf(m, __shfl_xor(m, 1));
    m = fmaxf(m, __shfl_xor(m, 2));
    m = fmaxf(m, __shfl_xor(m, 4));
    m = fmaxf(m, __shfl_xor(m, 8));
    float s = 0.f;
#pragma unroll
    for (int nt = 0; nt < 16; ++nt)
      if (nt < ntile) {
        vv[nt] = __expf(vv[nt] - m);
        s += vv[nt];
      }
    s += __shfl_xor(s, 1);
    s += __shfl_xor(s, 2);
    s += __shfl_xor(s, 4);
    s += __shfl_xor(s, 8);
    const float inv = 1.0f / s;
    const int sw = (prow & 7) << 3;     // P swizzle for this row
#pragma unroll
    for (int nt = 0; nt < 16; ++nt)
      if (nt < ntile) {
        const int col = nt * 16 + (l & 15);
        Pl[prow * 256 + (col ^ sw)] = f2bf(vv[nt] * inv);
      }
  }
  __syncthreads();
  // PV: waves split D (96 cols each); P read swizzled, V^T from global (L2)
  f32x4 o[4][6] = {};
  const int nks = SKV >> 5;
  for (int ks = 0; ks < nks; ++ks) {
    const int kk = ks * 32 + (l >> 4) * 8;
    bf8 av[4];
#pragma unroll
    for (int mt = 0; mt < 4; ++mt) {
      const int rp = mt * 16 + (l & 15);
      av[mt] = *(const bf8*)&Pl[rp * 256 + (kk ^ ((rp & 7) << 3))];
    }
#pragma unroll
    for (int nt = 0; nt < 6; ++nt) {
      const int d = w * 96 + nt * 16 + (l & 15);
      bf8 bv = *(const bf8*)&vt[(size_t)b * (H_ * T_) + (size_t)d * T_ + kk];
#pragma unroll
      for (int mt = 0; mt < 4; ++mt)
        o[mt][nt] = __builtin_amdgcn_mfma_f32_16x16x32_bf16(av[mt], bv, o[mt][nt], 0, 0, 0);
    }
  }
#pragma unroll
  for (int mt = 0; mt < 4; ++mt) {
    const int tok = b * T_ + t0 + mt * 16 + (l >> 4) * 4;
#pragma unroll
    for (int nt = 0; nt < 6; ++nt) {
      const int d = w * 96 + nt * 16 + (l & 15);
#pragma unroll
      for (int r = 0; r < 4; ++r)
        out[(size_t)(tok + r) * H_ + d] = o[mt][nt][r];
    }
  }
}

// ---------------------------------------------------------------------------
extern "C" void kernel_launch(void* const* d_in, const int* in_sizes, int n_in,
                              void* d_out, int out_size, void* d_ws, size_t ws_size,
                              hipStream_t stream) {
  (void)in_sizes; (void)n_in; (void)out_size; (void)ws_size;
  const float* x = (const float*)d_in[0];
  const float* wk = (const float*)d_in[1];
  const float* wq = (const float*)d_in[2];
  const float* wv = (const float*)d_in[3];
  float* out = (float*)d_out;
  char* ws = (char*)d_ws;
  const size_t SZ = (size_t)B_ * T_ * H_ * 2;
  short* kbuf = (short*)ws;
  short* qbuf = (short*)(ws + SZ);
  short* vt   = (short*)(ws + 2 * SZ);
  short* xb = (short*)d_out;
  short* wb = (short*)((char*)d_out + SZ);
  convert_kernel<<<2048, 256, 0, stream>>>(x, wk, wq, wv, xb, wb);
  proj_gemm<<<4608, 256, 0, stream>>>(xb, wb, kbuf, qbuf, vt);
  attn_kernel<<<1024, 256, 0, stream>>>(qbuf, kbuf, vt, out);
}

// Round 3
// 322.954 us; speedup vs baseline: 1.1457x; 1.0515x over previous
//
#include <hip/hip_runtime.h>

#define B_ 256
#define T_ 256
#define C_ 384
#define H_ 384

typedef float f4 __attribute__((ext_vector_type(4)));
typedef float f32x4 __attribute__((ext_vector_type(4)));
typedef short bf8 __attribute__((ext_vector_type(8)));
typedef short s8v __attribute__((ext_vector_type(8)));
typedef short s4v __attribute__((ext_vector_type(4)));

__device__ __forceinline__ short f2bf(float f) {
  unsigned u = __builtin_bit_cast(unsigned, f);
  u += 0x7FFFu + ((u >> 16) & 1u);   // RNE; inputs are finite
  return (short)(u >> 16);
}

__device__ __forceinline__ void gload_lds16(const void* g, void* l) {
  __builtin_amdgcn_global_load_lds(
      (const __attribute__((address_space(1))) unsigned int*)g,
      (__attribute__((address_space(3))) unsigned int*)l, 16, 0, 0);
}

// ---------------------------------------------------------------------------
// Kernel 1: fp32 -> bf16 conversion for x and the three weight matrices.
// ---------------------------------------------------------------------------
__global__ __launch_bounds__(256) void convert_kernel(
    const float* __restrict__ x, const float* __restrict__ wk,
    const float* __restrict__ wq, const float* __restrict__ wv,
    short* __restrict__ xb, short* __restrict__ wb) {
  const int NXG = (B_ * T_ * C_) / 8;
  const int NWG = (H_ * C_) / 8;
  const int total = NXG + 3 * NWG;
  for (int g = blockIdx.x * 256 + threadIdx.x; g < total; g += gridDim.x * 256) {
    const float* src;
    short* dst;
    if (g < NXG) {
      src = x + (size_t)g * 8;
      dst = xb + (size_t)g * 8;
    } else {
      int h = g - NXG;
      int wsel = h / NWG;
      int o = h - wsel * NWG;
      const float* wp = wsel == 0 ? wk : (wsel == 1 ? wq : wv);
      src = wp + (size_t)o * 8;
      dst = wb + (size_t)wsel * (H_ * C_) + (size_t)o * 8;
    }
    f4 f0 = *(const f4*)src;
    f4 f1 = *(const f4*)(src + 4);
    s8v r;
    r[0] = f2bf(f0[0]); r[1] = f2bf(f0[1]); r[2] = f2bf(f0[2]); r[3] = f2bf(f0[3]);
    r[4] = f2bf(f1[0]); r[5] = f2bf(f1[1]); r[6] = f2bf(f1[2]); r[7] = f2bf(f1[3]);
    *(s8v*)dst = r;
  }
}

// ---------------------------------------------------------------------------
// Kernel 2: QKV projection GEMM with T3+T4 pipeline.
// BM=256, BN=128, BK=64, 512 threads (8 waves, 4Mx2N, 64x64 per wave).
// Triple-buffered LDS (144 KB), counted vmcnt(12) across raw s_barriers:
// two K-tiles always in flight; never drain to 0 until the tail.
// T2 source-preswizzle (rule 21) keeps ds_read_b128 conflict-free.
// T1 XCD swizzle: grid 2304 = 8*288, bijective.
// ---------------------------------------------------------------------------
__global__ __launch_bounds__(512) void proj_gemm(
    const short* __restrict__ xb, const short* __restrict__ wb,
    short* __restrict__ kb, short* __restrict__ qbuf, short* __restrict__ vt) {
  __shared__ __align__(16) short lA[3][256 * 64];
  __shared__ __align__(16) short lB[3][128 * 64];
  const int tid = threadIdx.x;
  const int bid = blockIdx.x;
  const int swz = (bid & 7) * 288 + (bid >> 3);
  const int nb = swz % 9;
  const int mb = swz / 9;
  const int m0 = mb * 256, gn0 = nb * 128;
  const int w = tid >> 6, l = tid & 63;
  const int wr = w >> 1, wc = w & 1;

  // stage one K-tile (A: 256x64, B: 128x64) into buffer `buf`
  auto STAGE = [&](int buf, int t) {
    const int k0 = t * 64;
#pragma unroll
    for (int j = 0; j < 4; ++j) {
      const int flat = j * 512 + tid;
      const int row = flat >> 3;
      const int colg = ((flat & 7) ^ (row & 7)) * 8;
      gload_lds16(xb + (size_t)(m0 + row) * C_ + k0 + colg,
                  (char*)&lA[buf][0] + flat * 16);
    }
#pragma unroll
    for (int j = 0; j < 2; ++j) {
      const int flat = j * 512 + tid;
      const int row = flat >> 3;
      const int colg = ((flat & 7) ^ (row & 7)) * 8;
      gload_lds16(wb + (size_t)(gn0 + row) * C_ + k0 + colg,
                  (char*)&lB[buf][0] + flat * 16);
    }
  };

  f32x4 acc[4][4] = {};
  STAGE(0, 0);
  STAGE(1, 1);
  STAGE(2, 2);
#pragma unroll
  for (int t = 0; t < 6; ++t) {
    const int cur = t % 3;
    // wait only for the OLDEST staged tile; keep 12 loads (2 tiles) in flight
    if (t < 4)      asm volatile("s_waitcnt vmcnt(12)" ::: "memory");
    else if (t == 4) asm volatile("s_waitcnt vmcnt(6)" ::: "memory");
    else             asm volatile("s_waitcnt vmcnt(0)" ::: "memory");
    __builtin_amdgcn_s_barrier();      // raw: no vmcnt(0) drain
    __builtin_amdgcn_sched_barrier(0);
    const short* A = &lA[cur][0];
    const short* Bt = &lB[cur][0];
#pragma unroll
    for (int q = 0; q < 4; ++q) {      // 4 quadrant-phases per K-step
      const int mtp = q >> 1, ntp = q & 1;
      bf8 av[2][2], bv[2][2];
#pragma unroll
      for (int ks = 0; ks < 2; ++ks) {
        const int kg = ks * 4 + (l >> 4);
#pragma unroll
        for (int i = 0; i < 2; ++i) {
          const int ra = wr * 64 + (mtp * 2 + i) * 16 + (l & 15);
          av[ks][i] = *(const bf8*)&A[ra * 64 + ((kg ^ (ra & 7)) << 3)];
          const int rb = wc * 64 + (ntp * 2 + i) * 16 + (l & 15);
          bv[ks][i] = *(const bf8*)&Bt[rb * 64 + ((kg ^ (rb & 7)) << 3)];
        }
      }
      __builtin_amdgcn_s_setprio(1);
#pragma unroll
      for (int ks = 0; ks < 2; ++ks)
#pragma unroll
        for (int i = 0; i < 2; ++i)
#pragma unroll
          for (int jj = 0; jj < 2; ++jj)
            acc[mtp * 2 + i][ntp * 2 + jj] =
                __builtin_amdgcn_mfma_f32_16x16x32_bf16(
                    av[ks][i], bv[ks][jj], acc[mtp * 2 + i][ntp * 2 + jj],
                    0, 0, 0);
      __builtin_amdgcn_s_setprio(0);
    }
    __builtin_amdgcn_sched_barrier(0);
    __builtin_amdgcn_s_barrier();      // all waves done reading buf[cur]
    if (t < 3) STAGE(cur, t + 3);      // re-stage it for tile t+3
  }
  // epilogue (per-wave 64x64, same C/D mapping as before)
  const int proj = nb / 3;
  const int gcb = (nb % 3) * 128 + wc * 64 + (l & 15);
  const int tok0 = m0 + wr * 64 + ((l >> 4) * 4);
  if (proj < 2) {
    short* dst = proj == 0 ? kb : qbuf;
#pragma unroll
    for (int mt = 0; mt < 4; ++mt)
#pragma unroll
      for (int nt = 0; nt < 4; ++nt)
#pragma unroll
        for (int r = 0; r < 4; ++r)
          dst[(size_t)(tok0 + mt * 16 + r) * H_ + gcb + nt * 16] =
              f2bf(acc[mt][nt][r]);
  } else {
    const int bb = tok0 >> 8;
    const int tl0 = tok0 & 255;
#pragma unroll
    for (int mt = 0; mt < 4; ++mt)
#pragma unroll
      for (int nt = 0; nt < 4; ++nt) {
        s4v pk;
        pk[0] = f2bf(acc[mt][nt][0]); pk[1] = f2bf(acc[mt][nt][1]);
        pk[2] = f2bf(acc[mt][nt][2]); pk[3] = f2bf(acc[mt][nt][3]);
        *(s4v*)&vt[(size_t)bb * (H_ * T_) + (size_t)(gcb + nt * 16) * T_ +
                   tl0 + mt * 16] = pk;
      }
  }
}

// ---------------------------------------------------------------------------
// Kernel 3: causal attention (structure unchanged from round 2).
// New: XCD batch-grouping swizzle so the 4 q-blocks of each batch land on the
// same XCD and share K/V through that XCD's L2.
// ---------------------------------------------------------------------------
__global__ __launch_bounds__(256) void attn_kernel(
    const short* __restrict__ qbuf, const short* __restrict__ kb,
    const short* __restrict__ vt, float* __restrict__ out) {
  __shared__ __align__(16) char smem[40960];
  short* Kl = (short*)smem;
  short* Ql = (short*)(smem + 32768);
  short* Pl = (short*)smem;
  const int bid = blockIdx.x;
  const int swzb = (bid & 7) * 128 + (bid >> 3);  // 1024 = 8*128, bijective
  const int b = swzb >> 2;
  const int qi = swzb & 3;
  const int t0 = qi * 64;
  const int SKV = t0 + 64;
  const int ntile = SKV >> 4;
  const int tid = threadIdx.x;
  const int w = tid >> 6, l = tid & 63;
  f32x4 sa[16] = {};
  for (int hc = 0; hc < 6; ++hc) {
    const int h0 = hc * 64;
#pragma unroll
    for (int j = 0; j < 2; ++j) {
      const int flat = j * 256 + tid;
      const int row = flat >> 3;
      const int colg = ((flat & 7) ^ (row & 7)) * 8;
      gload_lds16(qbuf + (size_t)(b * T_ + t0 + row) * H_ + h0 + colg,
                  (char*)Ql + flat * 16);
    }
    const int kiss = SKV >> 5;
    for (int j = 0; j < kiss; ++j) {
      const int flat = j * 256 + tid;
      const int row = flat >> 3;
      const int colg = ((flat & 7) ^ (row & 7)) * 8;
      gload_lds16(kb + (size_t)(b * T_ + row) * H_ + h0 + colg,
                  (char*)Kl + flat * 16);
    }
    __syncthreads();
#pragma unroll
    for (int ks = 0; ks < 2; ++ks) {
      const int kg = ks * 4 + (l >> 4);
      const int rq = w * 16 + (l & 15);
      bf8 av = *(const bf8*)&Ql[rq * 64 + ((kg ^ (rq & 7)) << 3)];
#pragma unroll
      for (int nt = 0; nt < 16; ++nt)
        if (nt < ntile) {
          const int rk = nt * 16 + (l & 15);
          bf8 bv = *(const bf8*)&Kl[rk * 64 + ((kg ^ (rk & 7)) << 3)];
          sa[nt] = __builtin_amdgcn_mfma_f32_16x16x32_bf16(av, bv, sa[nt], 0, 0, 0);
        }
    }
    __syncthreads();
  }
  const float scale = 0.05103103630798287f;  // 384^-0.5
  const int rbl = w * 16 + (l >> 4) * 4;
#pragma unroll
  for (int r = 0; r < 4; ++r) {
    const int prow = rbl + r;
    const int trow = t0 + prow;
    float vv[16];
    float m = -3.0e38f;
#pragma unroll
    for (int nt = 0; nt < 16; ++nt)
      if (nt < ntile) {
        const int col = nt * 16 + (l & 15);
        float v = sa[nt][r] * scale;
        if (col > trow) v = -3.0e38f;
        vv[nt] = v;
        m = fmaxf(m, v);
      }
    m = fmaxf(m, __shfl_xor(m, 1));
    m = fmaxf(m, __shfl_xor(m, 2));
    m = fmaxf(m, __shfl_xor(m, 4));
    m = fmaxf(m, __shfl_xor(m, 8));
    float s = 0.f;
#pragma unroll
    for (int nt = 0; nt < 16; ++nt)
      if (nt < ntile) {
        vv[nt] = __expf(vv[nt] - m);
        s += vv[nt];
      }
    s += __shfl_xor(s, 1);
    s += __shfl_xor(s, 2);
    s += __shfl_xor(s, 4);
    s += __shfl_xor(s, 8);
    const float inv = 1.0f / s;
    const int sw = (prow & 7) << 3;
#pragma unroll
    for (int nt = 0; nt < 16; ++nt)
      if (nt < ntile) {
        const int col = nt * 16 + (l & 15);
        Pl[prow * 256 + (col ^ sw)] = f2bf(vv[nt] * inv);
      }
  }
  __syncthreads();
  f32x4 o[4][6] = {};
  const int nks = SKV >> 5;
  for (int ks = 0; ks < nks; ++ks) {
    const int kk = ks * 32 + (l >> 4) * 8;
    bf8 av[4];
#pragma unroll
    for (int mt = 0; mt < 4; ++mt) {
      const int rp = mt * 16 + (l & 15);
      av[mt] = *(const bf8*)&Pl[rp * 256 + (kk ^ ((rp & 7) << 3))];
    }
#pragma unroll
    for (int nt = 0; nt < 6; ++nt) {
      const int d = w * 96 + nt * 16 + (l & 15);
      bf8 bv = *(const bf8*)&vt[(size_t)b * (H_ * T_) + (size_t)d * T_ + kk];
#pragma unroll
      for (int mt = 0; mt < 4; ++mt)
        o[mt][nt] = __builtin_amdgcn_mfma_f32_16x16x32_bf16(av[mt], bv, o[mt][nt], 0, 0, 0);
    }
  }
#pragma unroll
  for (int mt = 0; mt < 4; ++mt) {
    const int tok = b * T_ + t0 + mt * 16 + (l >> 4) * 4;
#pragma unroll
    for (int nt = 0; nt < 6; ++nt) {
      const int d = w * 96 + nt * 16 + (l & 15);
#pragma unroll
      for (int r = 0; r < 4; ++r)
        out[(size_t)(tok + r) * H_ + d] = o[mt][nt][r];
    }
  }
}

// ---------------------------------------------------------------------------
extern "C" void kernel_launch(void* const* d_in, const int* in_sizes, int n_in,
                              void* d_out, int out_size, void* d_ws, size_t ws_size,
                              hipStream_t stream) {
  (void)in_sizes; (void)n_in; (void)out_size; (void)ws_size;
  const float* x = (const float*)d_in[0];
  const float* wk = (const float*)d_in[1];
  const float* wq = (const float*)d_in[2];
  const float* wv = (const float*)d_in[3];
  float* out = (float*)d_out;
  char* ws = (char*)d_ws;
  const size_t SZ = (size_t)B_ * T_ * H_ * 2;
  short* kbuf = (short*)ws;
  short* qbuf = (short*)(ws + SZ);
  short* vt   = (short*)(ws + 2 * SZ);
  short* xb = (short*)d_out;
  short* wb = (short*)((char*)d_out + SZ);
  convert_kernel<<<2048, 256, 0, stream>>>(x, wk, wq, wv, xb, wb);
  proj_gemm<<<2304, 512, 0, stream>>>(xb, wb, kbuf, qbuf, vt);
  attn_kernel<<<1024, 256, 0, stream>>>(qbuf, kbuf, vt, out);
}